// Round 3
// baseline (64.405 us; speedup 1.0000x reference)
//
#include <hip/hip_runtime.h>
#include <math.h>

// Problem constants (from reference setup_inputs)
#define NB      32      // batch
#define NKV     8       // kv heads
#define NQ      32      // query heads
#define GQ      4       // GQA group size = NQ/NKV
#define DH      128     // head dim
#define TPP     16      // tokens per page
#define PPS     128     // pages per slot
#define NPAGES  4096    // total pages
#define NSPLIT  8       // S-splits per (b,kv)
#define NBK     (NB*NKV)        // 256 (b,kv) pairs
#define PAGE_F  (TPP*DH)        // floats per page = 2048
#define PART_F  (GQ*DH + 2*GQ)  // partial size: o[4][128] + m[4] + l[4] = 520

// ---------------------------------------------------------------------------
// Kernel 1: per-(sp, b, kv) flash-style partial attention over an interleaved
// subset of pages (p = sp, sp+8, ...). Block index is SP-MAJOR so the ~8
// blocks co-resident on one CU come from 8 different (b,kv) pairs -> per-CU
// work is near the mean page count instead of the max (load balance).
// ---------------------------------------------------------------------------
__global__ __launch_bounds__(256) void pa_partial(
    const float* __restrict__ query,
    const float* __restrict__ key_pages,
    const float* __restrict__ value_pages,
    const int*   __restrict__ page_map,
    const int*   __restrict__ seq_lengths,
    float*       __restrict__ ws)
{
    const int blk = blockIdx.x;          // sp*NBK + (b*NKV + kv)
    const int sp  = blk >> 8;            // NBK = 256
    const int bk  = blk & (NBK - 1);
    const int kv  = bk & (NKV - 1);
    const int b   = bk >> 3;
    const int tid = threadIdx.x;

    const int seq     = seq_lengths[b];
    const int n_pages = (seq + TPP - 1) / TPP;
    if (sp >= n_pages) return;           // combine kernel skips inactive splits

    __shared__ __align__(16) float kbuf[TPP * DH];   // 8 KB
    __shared__ __align__(16) float vbuf[TPP * DH];   // 8 KB
    __shared__ float s_sc[GQ][TPP];

    // score-phase mapping: wave wv handles tokens 4*wv..4*wv+3; 16-lane groups
    // share a token; each lane covers 8 d-elements.
    const int lane = tid & 63;
    const int wv   = tid >> 6;
    const int tok  = wv * 4 + (lane >> 4);
    const int l16  = lane & 15;
    const int d0   = l16 * 8;

    // PV/output mapping: thread covers (gA, d) and (gB, d)
    const int d  = tid & 127;
    const int gA = tid >> 7;     // 0 or 1
    const int gB = gA + 2;       // 2 or 3

    // Q fragments (per-lane d-slice, all 4 group heads)
    float qreg[GQ][8];
    #pragma unroll
    for (int g = 0; g < GQ; ++g) {
        const float4* qp = (const float4*)(query + (size_t)((b * NQ + kv * GQ + g) * DH + d0));
        const float4 a = qp[0], c = qp[1];
        qreg[g][0] = a.x; qreg[g][1] = a.y; qreg[g][2] = a.z; qreg[g][3] = a.w;
        qreg[g][4] = c.x; qreg[g][5] = c.y; qreg[g][6] = c.z; qreg[g][7] = c.w;
    }

    float mA = -INFINITY, mB = -INFINITY;
    float lA = 0.f, lB = 0.f;
    float accA = 0.f, accB = 0.f;

    for (int p = sp; p < n_pages; p += NSPLIT) {
        const int pg = page_map[b * PPS + p];
        const float4* kg = (const float4*)(key_pages   + (size_t)(kv * NPAGES + pg) * PAGE_F);
        const float4* vg = (const float4*)(value_pages + (size_t)(kv * NPAGES + pg) * PAGE_F);

        __syncthreads();   // protect LDS from previous iteration's readers
        {
            float4* kb = (float4*)kbuf;
            float4* vb = (float4*)vbuf;
            kb[tid]       = kg[tid];
            kb[tid + 256] = kg[tid + 256];
            vb[tid]       = vg[tid];
            vb[tid + 256] = vg[tid + 256];
        }
        __syncthreads();

        // ---- scores: s[g][tok] = q[g] . k[tok] ----
        float part0, part1, part2, part3;
        {
            const float4 k0 = *(const float4*)&kbuf[tok * DH + d0];
            const float4 k1 = *(const float4*)&kbuf[tok * DH + d0 + 4];
            part0 = qreg[0][0]*k0.x + qreg[0][1]*k0.y + qreg[0][2]*k0.z + qreg[0][3]*k0.w
                  + qreg[0][4]*k1.x + qreg[0][5]*k1.y + qreg[0][6]*k1.z + qreg[0][7]*k1.w;
            part1 = qreg[1][0]*k0.x + qreg[1][1]*k0.y + qreg[1][2]*k0.z + qreg[1][3]*k0.w
                  + qreg[1][4]*k1.x + qreg[1][5]*k1.y + qreg[1][6]*k1.z + qreg[1][7]*k1.w;
            part2 = qreg[2][0]*k0.x + qreg[2][1]*k0.y + qreg[2][2]*k0.z + qreg[2][3]*k0.w
                  + qreg[2][4]*k1.x + qreg[2][5]*k1.y + qreg[2][6]*k1.z + qreg[2][7]*k1.w;
            part3 = qreg[3][0]*k0.x + qreg[3][1]*k0.y + qreg[3][2]*k0.z + qreg[3][3]*k0.w
                  + qreg[3][4]*k1.x + qreg[3][5]*k1.y + qreg[3][6]*k1.z + qreg[3][7]*k1.w;
            #pragma unroll
            for (int off = 8; off >= 1; off >>= 1) {
                part0 += __shfl_xor(part0, off);
                part1 += __shfl_xor(part1, off);
                part2 += __shfl_xor(part2, off);
                part3 += __shfl_xor(part3, off);
            }
        }
        const int tglob = p * TPP + tok;
        if (l16 < GQ) {
            const float val = (l16 == 0) ? part0 : (l16 == 1) ? part1
                            : (l16 == 2) ? part2 : part3;
            s_sc[l16][tok] = (tglob < seq) ? val : -1e30f;   // masked -> weight 0
        }
        __syncthreads();

        // ---- online softmax update (heads gA, gB per thread) ----
        float sA[TPP], sB[TPP];
        #pragma unroll
        for (int t = 0; t < TPP; ++t) { sA[t] = s_sc[gA][t]; sB[t] = s_sc[gB][t]; }

        float pA = -1e30f, pB = -1e30f;
        #pragma unroll
        for (int t = 0; t < TPP; ++t) { pA = fmaxf(pA, sA[t]); pB = fmaxf(pB, sB[t]); }

        const float mnA = fmaxf(mA, pA), mnB = fmaxf(mB, pB);
        const float scA = __expf(mA - mnA), scB = __expf(mB - mnB);
        mA = mnA; mB = mnB;

        float sumA = 0.f, sumB = 0.f;
        #pragma unroll
        for (int t = 0; t < TPP; ++t) {
            sA[t] = __expf(sA[t] - mnA); sumA += sA[t];
            sB[t] = __expf(sB[t] - mnB); sumB += sB[t];
        }
        lA = lA * scA + sumA;
        lB = lB * scB + sumB;
        accA *= scA;
        accB *= scB;

        // ---- PV accumulate: lanes read consecutive d -> conflict-free ----
        #pragma unroll
        for (int t = 0; t < TPP; ++t) {
            const float v = vbuf[t * DH + d];
            accA += sA[t] * v;
            accB += sB[t] * v;
        }
    }

    // ---- write partial (o unnormalized, m, l); layout is (b,kv)-major so
    // pa_combine is unchanged ----
    float* base = ws + (size_t)(bk * NSPLIT + sp) * PART_F;
    base[gA * DH + d] = accA;
    base[gB * DH + d] = accB;
    if (d == 0) {  // tid 0 writes g0,g2 ; tid 128 writes g1,g3
        base[GQ * DH + gA]      = mA;
        base[GQ * DH + GQ + gA] = lA;
        base[GQ * DH + gB]      = mB;
        base[GQ * DH + GQ + gB] = lB;
    }
}

// ---------------------------------------------------------------------------
// Kernel 2: combine the <=8 split partials per (b, kv) and write the output.
// ---------------------------------------------------------------------------
__global__ __launch_bounds__(256) void pa_combine(
    const float* __restrict__ ws,
    const int*   __restrict__ seq_lengths,
    float*       __restrict__ out)
{
    const int blk = blockIdx.x;    // b*NKV + kv
    const int b   = blk >> 3;
    const int kv  = blk & 7;
    const int tid = threadIdx.x;
    const int d   = tid & 127;
    const int gA  = tid >> 7;
    const int gB  = gA + 2;

    const int seq     = seq_lengths[b];
    const int n_pages = (seq + TPP - 1) / TPP;
    const int ns      = (n_pages < NSPLIT) ? n_pages : NSPLIT;

    const float* base0 = ws + (size_t)blk * NSPLIT * PART_F;

    float MA = -INFINITY, MB = -INFINITY;
    for (int si = 0; si < ns; ++si) {
        const float* p = base0 + si * PART_F;
        MA = fmaxf(MA, p[GQ * DH + gA]);
        MB = fmaxf(MB, p[GQ * DH + gB]);
    }

    float LA = 0.f, LB = 0.f, oA = 0.f, oB = 0.f;
    for (int si = 0; si < ns; ++si) {
        const float* p = base0 + si * PART_F;
        const float eA = __expf(p[GQ * DH + gA] - MA);
        const float eB = __expf(p[GQ * DH + gB] - MB);
        LA += p[GQ * DH + GQ + gA] * eA;
        LB += p[GQ * DH + GQ + gB] * eB;
        oA += p[gA * DH + d] * eA;
        oB += p[gB * DH + d] * eB;
    }

    float* ob = out + (size_t)(b * NQ + kv * GQ) * DH;
    ob[gA * DH + d] = oA / LA;
    ob[gB * DH + d] = oB / LB;
}

// ---------------------------------------------------------------------------
extern "C" void kernel_launch(void* const* d_in, const int* in_sizes, int n_in,
                              void* d_out, int out_size, void* d_ws, size_t ws_size,
                              hipStream_t stream)
{
    const float* query       = (const float*)d_in[0];
    const float* key_pages   = (const float*)d_in[1];
    const float* value_pages = (const float*)d_in[2];
    const int*   page_map    = (const int*)d_in[3];
    const int*   seq_lengths = (const int*)d_in[4];
    float*       out         = (float*)d_out;
    float*       ws          = (float*)d_ws;

    // ws usage: NB*NKV*NSPLIT * PART_F floats = 2048 * 520 * 4B ~= 4.26 MB
    pa_partial<<<NSPLIT * NBK, 256, 0, stream>>>(
        query, key_pages, value_pages, page_map, seq_lengths, ws);
    pa_combine<<<NBK, 256, 0, stream>>>(ws, seq_lengths, out);
}

// Round 4
// 61.038 us; speedup vs baseline: 1.0552x; 1.0552x over previous
//
#include <hip/hip_runtime.h>
#include <math.h>

// Problem constants (from reference setup_inputs)
#define NB      32      // batch
#define NKV     8       // kv heads
#define NQ      32      // query heads
#define GQ      4       // GQA group size = NQ/NKV
#define DH      128     // head dim
#define TPP     16      // tokens per page
#define PPS     128     // pages per slot
#define NPAGES  4096    // total pages
#define NSPLIT  16      // S-splits per (b,kv)
#define NBK     (NB*NKV)        // 256 (b,kv) pairs
#define PAGE_F  (TPP*DH)        // floats per page = 2048
#define PART_F  (GQ*DH + 2*GQ)  // partial size: o[4][128] + m[4] + l[4] = 520

// ---------------------------------------------------------------------------
// Kernel 1: per-(b, kv, sp) flash-style partial attention over an interleaved
// subset of pages (p = sp, sp+NSPLIT, ...). bk-major block order (R1 layout:
// co-resident blocks on a CU are different batches -> balanced). Register
// prefetch (T14): page p+NSPLIT is loaded into VGPRs while page p computes,
// then spilled to LDS at the top of the next iteration -> HBM latency hides
// under compute without extra LDS (keeps 8-9 blocks/CU).
// ---------------------------------------------------------------------------
__global__ __launch_bounds__(256) void pa_partial(
    const float* __restrict__ query,
    const float* __restrict__ key_pages,
    const float* __restrict__ value_pages,
    const int*   __restrict__ page_map,
    const int*   __restrict__ seq_lengths,
    float*       __restrict__ ws)
{
    const int blk = blockIdx.x;          // (b*NKV + kv)*NSPLIT + sp
    const int sp  = blk & (NSPLIT - 1);
    const int bk  = blk / NSPLIT;
    const int kv  = bk & (NKV - 1);
    const int b   = bk >> 3;
    const int tid = threadIdx.x;

    const int seq     = seq_lengths[b];
    const int n_pages = (seq + TPP - 1) / TPP;
    if (sp >= n_pages) return;           // combine kernel skips inactive splits

    __shared__ __align__(16) float kbuf[TPP * DH];   // 8 KB
    __shared__ __align__(16) float vbuf[TPP * DH];   // 8 KB
    __shared__ float s_sc[GQ][TPP];

    // score-phase mapping: wave wv handles tokens 4*wv..4*wv+3; 16-lane groups
    // share a token; each lane covers 8 d-elements.
    const int lane = tid & 63;
    const int wv   = tid >> 6;
    const int tok  = wv * 4 + (lane >> 4);
    const int l16  = lane & 15;
    const int d0   = l16 * 8;

    // PV/output mapping: thread covers (gA, d) and (gB, d)
    const int d  = tid & 127;
    const int gA = tid >> 7;     // 0 or 1
    const int gB = gA + 2;       // 2 or 3

    // Q fragments (per-lane d-slice, all 4 group heads)
    float qreg[GQ][8];
    #pragma unroll
    for (int g = 0; g < GQ; ++g) {
        const float4* qp = (const float4*)(query + (size_t)((b * NQ + kv * GQ + g) * DH + d0));
        const float4 a = qp[0], c = qp[1];
        qreg[g][0] = a.x; qreg[g][1] = a.y; qreg[g][2] = a.z; qreg[g][3] = a.w;
        qreg[g][4] = c.x; qreg[g][5] = c.y; qreg[g][6] = c.z; qreg[g][7] = c.w;
    }

    const float4* kbase = (const float4*)(key_pages   + (size_t)kv * NPAGES * PAGE_F);
    const float4* vbase = (const float4*)(value_pages + (size_t)kv * NPAGES * PAGE_F);

    float mA = -INFINITY, mB = -INFINITY;
    float lA = 0.f, lB = 0.f;
    float accA = 0.f, accB = 0.f;

    // register staging for one page (64 B/thread = 4 x float4)
    float4 rk0, rk1, rv0, rv1;
    {
        const int pg = page_map[b * PPS + sp];
        const float4* kg = kbase + (size_t)pg * (PAGE_F / 4);
        const float4* vg = vbase + (size_t)pg * (PAGE_F / 4);
        rk0 = kg[tid]; rk1 = kg[tid + 256];
        rv0 = vg[tid]; rv1 = vg[tid + 256];
    }

    for (int p = sp; p < n_pages; p += NSPLIT) {
        __syncthreads();   // all readers of the previous page's LDS are done
        // spill staged page into LDS (compiler inserts the vmcnt wait here,
        // which lands AFTER the previous iteration's full compute phase)
        {
            float4* kb = (float4*)kbuf;
            float4* vb = (float4*)vbuf;
            kb[tid]       = rk0;
            kb[tid + 256] = rk1;
            vb[tid]       = rv0;
            vb[tid + 256] = rv1;
        }
        // issue next page's loads (land during this page's compute)
        const int pn = p + NSPLIT;
        if (pn < n_pages) {
            const int pg = page_map[b * PPS + pn];
            const float4* kg = kbase + (size_t)pg * (PAGE_F / 4);
            const float4* vg = vbase + (size_t)pg * (PAGE_F / 4);
            rk0 = kg[tid]; rk1 = kg[tid + 256];
            rv0 = vg[tid]; rv1 = vg[tid + 256];
        }
        __syncthreads();   // LDS writes visible

        // ---- scores: s[g][tok] = q[g] . k[tok] ----
        float part0, part1, part2, part3;
        {
            const float4 k0 = *(const float4*)&kbuf[tok * DH + d0];
            const float4 k1 = *(const float4*)&kbuf[tok * DH + d0 + 4];
            part0 = qreg[0][0]*k0.x + qreg[0][1]*k0.y + qreg[0][2]*k0.z + qreg[0][3]*k0.w
                  + qreg[0][4]*k1.x + qreg[0][5]*k1.y + qreg[0][6]*k1.z + qreg[0][7]*k1.w;
            part1 = qreg[1][0]*k0.x + qreg[1][1]*k0.y + qreg[1][2]*k0.z + qreg[1][3]*k0.w
                  + qreg[1][4]*k1.x + qreg[1][5]*k1.y + qreg[1][6]*k1.z + qreg[1][7]*k1.w;
            part2 = qreg[2][0]*k0.x + qreg[2][1]*k0.y + qreg[2][2]*k0.z + qreg[2][3]*k0.w
                  + qreg[2][4]*k1.x + qreg[2][5]*k1.y + qreg[2][6]*k1.z + qreg[2][7]*k1.w;
            part3 = qreg[3][0]*k0.x + qreg[3][1]*k0.y + qreg[3][2]*k0.z + qreg[3][3]*k0.w
                  + qreg[3][4]*k1.x + qreg[3][5]*k1.y + qreg[3][6]*k1.z + qreg[3][7]*k1.w;
            #pragma unroll
            for (int off = 8; off >= 1; off >>= 1) {
                part0 += __shfl_xor(part0, off);
                part1 += __shfl_xor(part1, off);
                part2 += __shfl_xor(part2, off);
                part3 += __shfl_xor(part3, off);
            }
        }
        const int tglob = p * TPP + tok;
        if (l16 < GQ) {
            const float val = (l16 == 0) ? part0 : (l16 == 1) ? part1
                            : (l16 == 2) ? part2 : part3;
            s_sc[l16][tok] = (tglob < seq) ? val : -1e30f;   // masked -> weight 0
        }
        __syncthreads();

        // ---- online softmax update (heads gA, gB per thread) ----
        float sA[TPP], sB[TPP];
        #pragma unroll
        for (int t = 0; t < TPP; ++t) { sA[t] = s_sc[gA][t]; sB[t] = s_sc[gB][t]; }

        float pA = -1e30f, pB = -1e30f;
        #pragma unroll
        for (int t = 0; t < TPP; ++t) { pA = fmaxf(pA, sA[t]); pB = fmaxf(pB, sB[t]); }

        const float mnA = fmaxf(mA, pA), mnB = fmaxf(mB, pB);
        const float scA = __expf(mA - mnA), scB = __expf(mB - mnB);
        mA = mnA; mB = mnB;

        float sumA = 0.f, sumB = 0.f;
        #pragma unroll
        for (int t = 0; t < TPP; ++t) {
            sA[t] = __expf(sA[t] - mnA); sumA += sA[t];
            sB[t] = __expf(sB[t] - mnB); sumB += sB[t];
        }
        lA = lA * scA + sumA;
        lB = lB * scB + sumB;
        accA *= scA;
        accB *= scB;

        // ---- PV accumulate: lanes read consecutive d -> conflict-free ----
        #pragma unroll
        for (int t = 0; t < TPP; ++t) {
            const float v = vbuf[t * DH + d];
            accA += sA[t] * v;
            accB += sB[t] * v;
        }
    }

    // ---- write partial (o unnormalized, m, l) ----
    float* base = ws + (size_t)(bk * NSPLIT + sp) * PART_F;
    base[gA * DH + d] = accA;
    base[gB * DH + d] = accB;
    if (d == 0) {  // tid 0 writes g0,g2 ; tid 128 writes g1,g3
        base[GQ * DH + gA]      = mA;
        base[GQ * DH + GQ + gA] = lA;
        base[GQ * DH + gB]      = mB;
        base[GQ * DH + GQ + gB] = lB;
    }
}

// ---------------------------------------------------------------------------
// Kernel 2: combine the <=NSPLIT split partials per (b, kv), write output.
// ---------------------------------------------------------------------------
__global__ __launch_bounds__(256) void pa_combine(
    const float* __restrict__ ws,
    const int*   __restrict__ seq_lengths,
    float*       __restrict__ out)
{
    const int blk = blockIdx.x;    // b*NKV + kv
    const int b   = blk >> 3;
    const int kv  = blk & 7;
    const int tid = threadIdx.x;
    const int d   = tid & 127;
    const int gA  = tid >> 7;
    const int gB  = gA + 2;

    const int seq     = seq_lengths[b];
    const int n_pages = (seq + TPP - 1) / TPP;
    const int ns      = (n_pages < NSPLIT) ? n_pages : NSPLIT;

    const float* base0 = ws + (size_t)blk * NSPLIT * PART_F;

    float MA = -INFINITY, MB = -INFINITY;
    for (int si = 0; si < ns; ++si) {
        const float* p = base0 + si * PART_F;
        MA = fmaxf(MA, p[GQ * DH + gA]);
        MB = fmaxf(MB, p[GQ * DH + gB]);
    }

    float LA = 0.f, LB = 0.f, oA = 0.f, oB = 0.f;
    for (int si = 0; si < ns; ++si) {
        const float* p = base0 + si * PART_F;
        const float eA = __expf(p[GQ * DH + gA] - MA);
        const float eB = __expf(p[GQ * DH + gB] - MB);
        LA += p[GQ * DH + GQ + gA] * eA;
        LB += p[GQ * DH + GQ + gB] * eB;
        oA += p[gA * DH + d] * eA;
        oB += p[gB * DH + d] * eB;
    }

    float* ob = out + (size_t)(b * NQ + kv * GQ) * DH;
    ob[gA * DH + d] = oA / LA;
    ob[gB * DH + d] = oB / LB;
}

// ---------------------------------------------------------------------------
extern "C" void kernel_launch(void* const* d_in, const int* in_sizes, int n_in,
                              void* d_out, int out_size, void* d_ws, size_t ws_size,
                              hipStream_t stream)
{
    const float* query       = (const float*)d_in[0];
    const float* key_pages   = (const float*)d_in[1];
    const float* value_pages = (const float*)d_in[2];
    const int*   page_map    = (const int*)d_in[3];
    const int*   seq_lengths = (const int*)d_in[4];
    float*       out         = (float*)d_out;
    float*       ws          = (float*)d_ws;

    // ws usage: NBK*NSPLIT * PART_F floats = 4096 * 520 * 4B ~= 8.5 MB
    pa_partial<<<NBK * NSPLIT, 256, 0, stream>>>(
        query, key_pages, value_pages, page_map, seq_lengths, ws);
    pa_combine<<<NBK, 256, 0, stream>>>(ws, seq_lengths, out);
}

// Round 5
// 58.038 us; speedup vs baseline: 1.1097x; 1.0517x over previous
//
#include <hip/hip_runtime.h>
#include <math.h>

// Problem constants (from reference setup_inputs)
#define NB      32      // batch
#define NKV     8       // kv heads
#define NQ      32      // query heads
#define GQ      4       // GQA group size = NQ/NKV
#define DH      128     // head dim
#define TPP     16      // tokens per page
#define PPS     128     // pages per slot
#define NPAGES  4096    // total pages
#define NSPLIT  16      // S-splits per (b,kv)
#define NBK     (NB*NKV)        // 256 (b,kv) pairs
#define PAGE_F  (TPP*DH)        // floats per page = 2048
#define PART_F  (GQ*DH + 2*GQ)  // partial size: o[4][128] + m[4] + l[4] = 520

// ---------------------------------------------------------------------------
// Kernel 1: barrier-free streaming paged attention partial.
// Block = (b, kv, sp). Each 16-lane group owns token slot `grp` of every
// page p = sp, sp+NSPLIT, ... and maintains its OWN online-softmax state
// (m, l, acc) entirely in registers; K and V rows stream global->register
// (no LDS staging, no per-page barriers). One LDS merge of the 16 group
// partials at block end, then the usual split-partial write to ws.
// ---------------------------------------------------------------------------
__global__ __launch_bounds__(256) void pa_partial(
    const float* __restrict__ query,
    const float* __restrict__ key_pages,
    const float* __restrict__ value_pages,
    const int*   __restrict__ page_map,
    const int*   __restrict__ seq_lengths,
    float*       __restrict__ ws)
{
    const int blk = blockIdx.x;          // (b*NKV + kv)*NSPLIT + sp
    const int sp  = blk & (NSPLIT - 1);
    const int bk  = blk >> 4;            // NSPLIT = 16
    const int kv  = bk & (NKV - 1);
    const int b   = bk >> 3;
    const int tid = threadIdx.x;

    const int seq     = seq_lengths[b];
    const int n_pages = (seq + TPP - 1) / TPP;
    if (sp >= n_pages) return;           // combine kernel skips inactive splits

    const int grp = tid >> 4;            // token slot 0..15 within a page
    const int l16 = tid & 15;            // lane within token group
    const int d0  = l16 * 8;             // this lane's 8-float d-slice

    // Q fragments (d-slice of all 4 group heads)
    float qreg[GQ][8];
    #pragma unroll
    for (int g = 0; g < GQ; ++g) {
        const float4* qp = (const float4*)(query + (size_t)((b * NQ + kv * GQ + g) * DH + d0));
        const float4 a = qp[0], c = qp[1];
        qreg[g][0] = a.x; qreg[g][1] = a.y; qreg[g][2] = a.z; qreg[g][3] = a.w;
        qreg[g][4] = c.x; qreg[g][5] = c.y; qreg[g][6] = c.z; qreg[g][7] = c.w;
    }

    const float* kbase = key_pages   + (size_t)kv * NPAGES * PAGE_F;
    const float* vbase = value_pages + (size_t)kv * NPAGES * PAGE_F;
    const int*   pmap  = page_map + b * PPS;

    // per-group online softmax state (finite init so masked-only groups stay
    // NaN-free: max(-1e30, -1e30) - (-1e30) = 0, exp(0)=1 selected to 0)
    float m[GQ] = {-1e30f, -1e30f, -1e30f, -1e30f};
    float l[GQ] = {0.f, 0.f, 0.f, 0.f};
    float acc[GQ][8] = {};

    // register staging: current page's K,V row-slices (64 B/thread)
    float4 ck0, ck1, cv0, cv1;
    {
        const size_t po = (size_t)pmap[sp] * PAGE_F + grp * DH + d0;
        const float4* kp = (const float4*)(kbase + po);
        const float4* vp = (const float4*)(vbase + po);
        ck0 = kp[0]; ck1 = kp[1];
        cv0 = vp[0]; cv1 = vp[1];
    }

    for (int p = sp; p < n_pages; p += NSPLIT) {
        // issue next page's loads first; they fly during this page's compute
        float4 nk0, nk1, nv0, nv1;
        const int pn = p + NSPLIT;
        if (pn < n_pages) {
            const size_t po = (size_t)pmap[pn] * PAGE_F + grp * DH + d0;
            const float4* kp = (const float4*)(kbase + po);
            const float4* vp = (const float4*)(vbase + po);
            nk0 = kp[0]; nk1 = kp[1];
            nv0 = vp[0]; nv1 = vp[1];
        }

        // ---- scores: s[g] = q[g] . K[grp]  (reduce across 16 lanes) ----
        const float kx[8] = {ck0.x, ck0.y, ck0.z, ck0.w, ck1.x, ck1.y, ck1.z, ck1.w};
        float s[GQ];
        #pragma unroll
        for (int g = 0; g < GQ; ++g) {
            float t = qreg[g][0]*kx[0] + qreg[g][1]*kx[1] + qreg[g][2]*kx[2] + qreg[g][3]*kx[3]
                    + qreg[g][4]*kx[4] + qreg[g][5]*kx[5] + qreg[g][6]*kx[6] + qreg[g][7]*kx[7];
            #pragma unroll
            for (int off = 8; off >= 1; off >>= 1) t += __shfl_xor(t, off);
            s[g] = t;
        }

        const bool valid = (p * TPP + grp) < seq;
        const float vx[8] = {cv0.x, cv0.y, cv0.z, cv0.w, cv1.x, cv1.y, cv1.z, cv1.w};

        // ---- per-group online softmax update (single token) ----
        #pragma unroll
        for (int g = 0; g < GQ; ++g) {
            const float mn = fmaxf(m[g], s[g]);
            float pc = __expf(s[g] - mn);
            pc = valid ? pc : 0.f;
            const float sc = __expf(m[g] - mn);
            m[g] = mn;
            l[g] = l[g] * sc + pc;
            #pragma unroll
            for (int j = 0; j < 8; ++j)
                acc[g][j] = acc[g][j] * sc + pc * vx[j];
        }

        ck0 = nk0; ck1 = nk1; cv0 = nv0; cv1 = nv1;   // SSA rename, free
    }

    // ---- block-level merge of the 16 group partials via LDS ----
    __shared__ float s_acc[16][GQ][DH];   // 32 KB
    __shared__ float s_m[16][GQ];
    __shared__ float s_l[16][GQ];

    #pragma unroll
    for (int g = 0; g < GQ; ++g) {
        *(float4*)&s_acc[grp][g][d0]     = make_float4(acc[g][0], acc[g][1], acc[g][2], acc[g][3]);
        *(float4*)&s_acc[grp][g][d0 + 4] = make_float4(acc[g][4], acc[g][5], acc[g][6], acc[g][7]);
    }
    if (l16 == 0) {
        #pragma unroll
        for (int g = 0; g < GQ; ++g) { s_m[grp][g] = m[g]; s_l[grp][g] = l[g]; }
    }
    __syncthreads();

    // remap: thread -> (gA, d) and (gB, d)
    const int d  = tid & 127;
    const int gA = tid >> 7;     // 0 or 1
    const int gB = gA + 2;       // 2 or 3

    float MA = -1e30f, MB = -1e30f;
    #pragma unroll
    for (int i = 0; i < 16; ++i) {
        MA = fmaxf(MA, s_m[i][gA]);
        MB = fmaxf(MB, s_m[i][gB]);
    }
    float LA = 0.f, LB = 0.f, oA = 0.f, oB = 0.f;
    #pragma unroll
    for (int i = 0; i < 16; ++i) {
        const float eA = __expf(s_m[i][gA] - MA);
        const float eB = __expf(s_m[i][gB] - MB);
        LA += s_l[i][gA] * eA;
        LB += s_l[i][gB] * eB;
        oA += s_acc[i][gA][d] * eA;
        oB += s_acc[i][gB][d] * eB;
    }

    // ---- write partial (o unnormalized, m, l); ws layout unchanged ----
    float* base = ws + (size_t)(bk * NSPLIT + sp) * PART_F;
    base[gA * DH + d] = oA;
    base[gB * DH + d] = oB;
    if (d == 0) {  // tid 0 writes g0,g2 ; tid 128 writes g1,g3
        base[GQ * DH + gA]      = MA;
        base[GQ * DH + GQ + gA] = LA;
        base[GQ * DH + gB]      = MB;
        base[GQ * DH + GQ + gB] = LB;
    }
}

// ---------------------------------------------------------------------------
// Kernel 2: combine the <=NSPLIT split partials per (b, kv), write output.
// ---------------------------------------------------------------------------
__global__ __launch_bounds__(256) void pa_combine(
    const float* __restrict__ ws,
    const int*   __restrict__ seq_lengths,
    float*       __restrict__ out)
{
    const int blk = blockIdx.x;    // b*NKV + kv
    const int b   = blk >> 3;
    const int kv  = blk & 7;
    const int tid = threadIdx.x;
    const int d   = tid & 127;
    const int gA  = tid >> 7;
    const int gB  = gA + 2;

    const int seq     = seq_lengths[b];
    const int n_pages = (seq + TPP - 1) / TPP;
    const int ns      = (n_pages < NSPLIT) ? n_pages : NSPLIT;

    const float* base0 = ws + (size_t)blk * NSPLIT * PART_F;

    float MA = -1e30f, MB = -1e30f;
    for (int si = 0; si < ns; ++si) {
        const float* p = base0 + si * PART_F;
        MA = fmaxf(MA, p[GQ * DH + gA]);
        MB = fmaxf(MB, p[GQ * DH + gB]);
    }

    float LA = 0.f, LB = 0.f, oA = 0.f, oB = 0.f;
    for (int si = 0; si < ns; ++si) {
        const float* p = base0 + si * PART_F;
        const float eA = __expf(p[GQ * DH + gA] - MA);
        const float eB = __expf(p[GQ * DH + gB] - MB);
        LA += p[GQ * DH + GQ + gA] * eA;
        LB += p[GQ * DH + GQ + gB] * eB;
        oA += p[gA * DH + d] * eA;
        oB += p[gB * DH + d] * eB;
    }

    float* ob = out + (size_t)(b * NQ + kv * GQ) * DH;
    ob[gA * DH + d] = oA / LA;
    ob[gB * DH + d] = oB / LB;
}

// ---------------------------------------------------------------------------
extern "C" void kernel_launch(void* const* d_in, const int* in_sizes, int n_in,
                              void* d_out, int out_size, void* d_ws, size_t ws_size,
                              hipStream_t stream)
{
    const float* query       = (const float*)d_in[0];
    const float* key_pages   = (const float*)d_in[1];
    const float* value_pages = (const float*)d_in[2];
    const int*   page_map    = (const int*)d_in[3];
    const int*   seq_lengths = (const int*)d_in[4];
    float*       out         = (float*)d_out;
    float*       ws          = (float*)d_ws;

    // ws usage: NBK*NSPLIT * PART_F floats = 4096 * 520 * 4B ~= 8.5 MB
    pa_partial<<<NBK * NSPLIT, 256, 0, stream>>>(
        query, key_pages, value_pages, page_map, seq_lengths, ws);
    pa_combine<<<NBK, 256, 0, stream>>>(ws, seq_lengths, out);
}